// Round 3
// baseline (768.202 us; speedup 1.0000x reference)
//
#include <hip/hip_runtime.h>
#include <hip/hip_bf16.h>
#include <stdint.h>

// ---------------- problem constants ----------------
#define D_MODEL   1024
#define SEQ       8192
#define BATCH     4
#define ROWS      (BATCH*SEQ)     // 32768 window-domain rows
#define NQKV      3072
#define HEADS     16
#define DKH       64

typedef _Float16 f16;
typedef f16   f16x8 __attribute__((ext_vector_type(8)));
typedef f16   f16x4 __attribute__((ext_vector_type(4)));
typedef float f32x4 __attribute__((ext_vector_type(4)));

#define AS1 __attribute__((address_space(1)))
#define AS3 __attribute__((address_space(3)))

__device__ __forceinline__ void lds_load16(const void* g, void* l) {
  __builtin_amdgcn_global_load_lds((const AS1 void*)g, (AS3 void*)l, 16, 0, 0);
}

// ---------------------------------------------------------------------------
// Kernel 1: convert + reorder weights (fp32 -> fp16).
//  w_qkv (1024 x 3072), col c = hh*192 + m (m = merged (d_k,3) index; chunk
//  happens on m, so n-domain col = t*1024 + hh*64 + j with t=m>>6, j=m&63)
//    -> w_qkvT f16 [n][k]  (transposed, row-major-K)
//  w_o (1024 x 1024) -> w_oT f16 [n][k]
//  b_qkv reordered to n-domain (fp32)
// ---------------------------------------------------------------------------
__global__ void cvt_weights(const float* __restrict__ wqkv,
                            const float* __restrict__ bqkv,
                            const float* __restrict__ wo,
                            f16* __restrict__ wqkvT,
                            float* __restrict__ bqkvR,
                            f16* __restrict__ woT)
{
  const int NW1 = NQKV * D_MODEL;      // 3145728
  const int NW2 = D_MODEL * D_MODEL;   // 1048576
  int i = blockIdx.x * 256 + threadIdx.x;
  if (i < NW1) {
    int c = i % NQKV, k = i / NQKV;            // coalesced read of wqkv
    int hh = c / 192, rr = c % 192;
    int t  = rr >> 6, a = rr & 63;
    int n  = t * 1024 + hh * 64 + a;
    wqkvT[(size_t)n * 1024 + k] = (f16)wqkv[i];
  } else if (i < NW1 + NW2) {
    int j = i - NW1;
    int n = j % D_MODEL, k = j / D_MODEL;      // coalesced read of wo
    woT[(size_t)n * 1024 + k] = (f16)wo[j];
  } else if (i < NW1 + NW2 + NQKV) {
    int c = i - NW1 - NW2;
    int hh = c / 192, rr = c % 192;
    int t  = rr >> 6, a = rr & 63;
    bqkvR[t * 1024 + hh * 64 + a] = bqkv[c];
  }
}

// ---------------------------------------------------------------------------
// Kernel 2: x fp32 -> fp16 with roll(-64) along sequence.
// xb[r] = x[batch(r), (pos(r)+64) mod 8192]. 8 elems/thread, 16B store.
// ---------------------------------------------------------------------------
__global__ void cvt_x(const float* __restrict__ x, f16* __restrict__ xb)
{
  int i  = blockIdx.x * 256 + threadIdx.x;  // one f16x8 per thread
  int r  = i >> 7;                          // 128 8-elem chunks per row
  int c8 = i & 127;
  int bb = r >> 13, p = r & 8191;
  int sr = (bb << 13) | ((p + 64) & 8191);
  const float* src = x + (size_t)sr * 1024 + c8 * 8;
  float4 v0 = *(const float4*)(src);
  float4 v1 = *(const float4*)(src + 4);
  f16x8 o = { (f16)v0.x, (f16)v0.y, (f16)v0.z, (f16)v0.w,
              (f16)v1.x, (f16)v1.y, (f16)v1.z, (f16)v1.w };
  *(f16x8*)(xb + (size_t)r * 1024 + c8 * 8) = o;
}

// ---------------------------------------------------------------------------
// NT GEMM (m97 structure): C[M,N] = A[M,K] * B^T[N,K], K=1024.
// 128x128 tile, BK=64, 256 threads (2x2 waves, 64x64 per wave),
// global_load_lds width 16 with XOR-pre-swizzled source, 2-barrier K loop.
// EPI=0: +bias, write Q/K row-major f16 and V transposed per (sub,head).
// EPI=1: +bias, write fp32 to d_out with roll(+64).
// ---------------------------------------------------------------------------
template<int EPI>
__global__ __launch_bounds__(256)
void gemm_bt(const f16* __restrict__ A, const f16* __restrict__ B,
             const float* __restrict__ bias,
             f16* __restrict__ outQ, f16* __restrict__ outK,
             f16* __restrict__ outVT, float* __restrict__ outF,
             int Ntiles)
{
  __shared__ alignas(16) char lds[32768];
  char* Asm = lds;            // A tile: [128][64] f16, 128B rows, XOR-swizzled
  char* Bsm = lds + 16384;    // B^T tile: same geometry

  // XCD-chunked swizzle (grid divisible by 8)
  int nwg  = gridDim.x;
  int cpx  = nwg >> 3;
  int work = (blockIdx.x & 7) * cpx + (blockIdx.x >> 3);
  int mt = work / Ntiles, nt = work % Ntiles;
  int m0 = mt * 128, n0 = nt * 128;

  int tid = threadIdx.x;
  int w = tid >> 6, l = tid & 63;
  int wr = w >> 1, wc = w & 1;
  int srow = l >> 3, sj = l & 7;     // staging: 8 rows x 8 chunks per instr
  int c16 = l & 15, g4 = l >> 4;

  const char* Ab = (const char*)A;
  const char* Bb = (const char*)B;

  f32x4 acc[4][4];
#pragma unroll
  for (int mi = 0; mi < 4; ++mi)
#pragma unroll
    for (int nj = 0; nj < 4; ++nj)
      acc[mi][nj] = (f32x4){0.f, 0.f, 0.f, 0.f};

  for (int kt = 0; kt < 16; ++kt) {
    int k0 = kt * 64;
#pragma unroll
    for (int q = 0; q < 4; ++q) {
      int r  = w * 32 + q * 8 + srow;          // tile row this lane stages
      int jg = sj ^ (r & 7);                   // pre-swizzled source chunk
      lds_load16(Ab + (size_t)(m0 + r) * 2048 + k0 * 2 + jg * 16,
                 Asm + (w * 32 + q * 8) * 128);
      lds_load16(Bb + (size_t)(n0 + r) * 2048 + k0 * 2 + jg * 16,
                 Bsm + (w * 32 + q * 8) * 128);
    }
    __syncthreads();   // compiler emits vmcnt(0) drain before barrier
#pragma unroll
    for (int kk = 0; kk < 2; ++kk) {
      f16x8 af[4], bfr[4];
#pragma unroll
      for (int mi = 0; mi < 4; ++mi) {
        int r  = wr * 64 + mi * 16 + c16;
        int ch = ((kk << 2) | g4) ^ (r & 7);
        af[mi] = *(const f16x8*)(Asm + r * 128 + ch * 16);
      }
#pragma unroll
      for (int nj = 0; nj < 4; ++nj) {
        int r  = wc * 64 + nj * 16 + c16;
        int ch = ((kk << 2) | g4) ^ (r & 7);
        bfr[nj] = *(const f16x8*)(Bsm + r * 128 + ch * 16);
      }
#pragma unroll
      for (int mi = 0; mi < 4; ++mi)
#pragma unroll
        for (int nj = 0; nj < 4; ++nj)
          acc[mi][nj] = __builtin_amdgcn_mfma_f32_16x16x32_f16(
              af[mi], bfr[nj], acc[mi][nj], 0, 0, 0);
    }
    __syncthreads();
  }

  // ---------------- epilogue ----------------
  int rbase = g4 * 4;
  if (EPI == 0) {
    int tt = n0 >> 10;   // block-uniform: 0=Q, 1=K, 2=V
#pragma unroll
    for (int mi = 0; mi < 4; ++mi) {
#pragma unroll
      for (int nj = 0; nj < 4; ++nj) {
        int n  = n0 + wc * 64 + nj * 16 + c16;
        int nn = n & 1023;
        float bv = bias[n];
#pragma unroll
        for (int j = 0; j < 4; ++j) {
          int m = m0 + wr * 64 + mi * 16 + rbase + j;
          float v = acc[mi][nj][j] + bv;
          if (tt == 0) {
            outQ[(size_t)m * 1024 + nn] = (f16)v;
          } else if (tt == 1) {
            outK[(size_t)m * 1024 + nn] = (f16)v;
          } else {
            int sub = m >> 6, key = m & 63;
            int hh = nn >> 6, dk = nn & 63;
            outVT[(((size_t)(sub * 16 + hh) * 64 + dk) << 6) + key] = (f16)v;
          }
        }
      }
    }
  } else {
#pragma unroll
    for (int mi = 0; mi < 4; ++mi) {
#pragma unroll
      for (int nj = 0; nj < 4; ++nj) {
        int n = n0 + wc * 64 + nj * 16 + c16;
        float bv = bias[n];
#pragma unroll
        for (int j = 0; j < 4; ++j) {
          int m = m0 + wr * 64 + mi * 16 + rbase + j;
          int bb = m >> 13, p = m & 8191;
          int dr = (bb << 13) | ((p + 64) & 8191);   // roll(+64)
          outF[(size_t)dr * 1024 + n] = acc[mi][nj][j] + bv;
        }
      }
    }
  }
}

// ---------------------------------------------------------------------------
// Kernel 4: block-diagonal attention. One wave per (sub-block, head):
// Q,K: 64x64 from row-major buffers; V from transposed buffer.
// S = Q K^T (MFMA) -> wave-parallel softmax (shfl_xor within 16-lane groups)
// -> P via XOR-swizzled LDS -> O = P V (MFMA) -> f16 to A2[row][h*64+dk].
// ---------------------------------------------------------------------------
__global__ __launch_bounds__(64)
void attn64(const f16* __restrict__ Q, const f16* __restrict__ Kb,
            const f16* __restrict__ VT, f16* __restrict__ O)
{
  __shared__ alignas(16) char plds[8192];   // P: [64][64] f16, swizzled
  int u = blockIdx.x;
  int sub = u >> 4, hh = u & 15;
  int l = threadIdx.x;
  int c = l & 15, g = l >> 4;

  const char* Qb = (const char*)Q  + (size_t)sub * 64 * 2048 + hh * 128;
  const char* KB = (const char*)Kb + (size_t)sub * 64 * 2048 + hh * 128;
  const char* VB = (const char*)VT + (size_t)u * 8192;

  f16x8 aq[4][2], bk[4][2];
#pragma unroll
  for (int mi = 0; mi < 4; ++mi)
#pragma unroll
    for (int kb = 0; kb < 2; ++kb)
      aq[mi][kb] = *(const f16x8*)(Qb + (mi * 16 + c) * 2048 + (kb * 32 + g * 8) * 2);
#pragma unroll
  for (int nj = 0; nj < 4; ++nj)
#pragma unroll
    for (int kb = 0; kb < 2; ++kb)
      bk[nj][kb] = *(const f16x8*)(KB + (nj * 16 + c) * 2048 + (kb * 32 + g * 8) * 2);

  f32x4 s[4][4];
#pragma unroll
  for (int mi = 0; mi < 4; ++mi)
#pragma unroll
    for (int nj = 0; nj < 4; ++nj)
      s[mi][nj] = (f32x4){0.f, 0.f, 0.f, 0.f};
#pragma unroll
  for (int kb = 0; kb < 2; ++kb)
#pragma unroll
    for (int mi = 0; mi < 4; ++mi)
#pragma unroll
      for (int nj = 0; nj < 4; ++nj)
        s[mi][nj] = __builtin_amdgcn_mfma_f32_16x16x32_f16(
            aq[mi][kb], bk[nj][kb], s[mi][nj], 0, 0, 0);

  // softmax over keys (row r = mi*16 + g*4 + j; cols spread over c and nj)
  const float SM_SCALE = 0.125f * 1.44269504089f;   // (1/sqrt(64))*log2(e)
#pragma unroll
  for (int mi = 0; mi < 4; ++mi) {
#pragma unroll
    for (int j = 0; j < 4; ++j) {
      float v0 = s[mi][0][j], v1 = s[mi][1][j], v2 = s[mi][2][j], v3 = s[mi][3][j];
      float mx = fmaxf(fmaxf(v0, v1), fmaxf(v2, v3));
      mx = fmaxf(mx, __shfl_xor(mx, 1));
      mx = fmaxf(mx, __shfl_xor(mx, 2));
      mx = fmaxf(mx, __shfl_xor(mx, 4));
      mx = fmaxf(mx, __shfl_xor(mx, 8));
      float p0 = exp2f((v0 - mx) * SM_SCALE);
      float p1 = exp2f((v1 - mx) * SM_SCALE);
      float p2 = exp2f((v2 - mx) * SM_SCALE);
      float p3 = exp2f((v3 - mx) * SM_SCALE);
      float sm = (p0 + p1) + (p2 + p3);
      sm += __shfl_xor(sm, 1);
      sm += __shfl_xor(sm, 2);
      sm += __shfl_xor(sm, 4);
      sm += __shfl_xor(sm, 8);
      float inv = 1.0f / sm;
      int r = mi * 16 + g * 4 + j;
      int rbyte = r * 128, rx = (r & 7) << 4;
      {
        int key = c;
        *(f16*)(plds + rbyte + (((key >> 3) << 4) ^ rx) + ((key & 7) << 1)) = (f16)(p0 * inv);
      }
      {
        int key = 16 + c;
        *(f16*)(plds + rbyte + (((key >> 3) << 4) ^ rx) + ((key & 7) << 1)) = (f16)(p1 * inv);
      }
      {
        int key = 32 + c;
        *(f16*)(plds + rbyte + (((key >> 3) << 4) ^ rx) + ((key & 7) << 1)) = (f16)(p2 * inv);
      }
      {
        int key = 48 + c;
        *(f16*)(plds + rbyte + (((key >> 3) << 4) ^ rx) + ((key & 7) << 1)) = (f16)(p3 * inv);
      }
    }
  }
  __syncthreads();

  f16x8 ap[4][2], bv[4][2];
#pragma unroll
  for (int mi = 0; mi < 4; ++mi) {
    int rowq = mi * 16 + c;
    int base = rowq * 128, rx = rowq & 7;
#pragma unroll
    for (int kb = 0; kb < 2; ++kb) {
      int ch = ((kb << 2) | g) ^ rx;
      ap[mi][kb] = *(const f16x8*)(plds + base + (ch << 4));
    }
  }
#pragma unroll
  for (int nj = 0; nj < 4; ++nj) {
    int dk = nj * 16 + c;
#pragma unroll
    for (int kb = 0; kb < 2; ++kb)
      bv[nj][kb] = *(const f16x8*)(VB + (dk * 64 + kb * 32 + g * 8) * 2);
  }

  f32x4 o[4][4];
#pragma unroll
  for (int mi = 0; mi < 4; ++mi)
#pragma unroll
    for (int nj = 0; nj < 4; ++nj)
      o[mi][nj] = (f32x4){0.f, 0.f, 0.f, 0.f};
#pragma unroll
  for (int kb = 0; kb < 2; ++kb)
#pragma unroll
    for (int mi = 0; mi < 4; ++mi)
#pragma unroll
      for (int nj = 0; nj < 4; ++nj)
        o[mi][nj] = __builtin_amdgcn_mfma_f32_16x16x32_f16(
            ap[mi][kb], bv[nj][kb], o[mi][nj], 0, 0, 0);

#pragma unroll
  for (int mi = 0; mi < 4; ++mi)
#pragma unroll
    for (int nj = 0; nj < 4; ++nj)
#pragma unroll
      for (int j = 0; j < 4; ++j) {
        int qrow = mi * 16 + g * 4 + j;
        int dk = nj * 16 + c;
        O[(size_t)(sub * 64 + qrow) * 1024 + hh * 64 + dk] = (f16)o[mi][nj][j];
      }
}

// ---------------------------------------------------------------------------
// launch
// ---------------------------------------------------------------------------
extern "C" void kernel_launch(void* const* d_in, const int* in_sizes, int n_in,
                              void* d_out, int out_size, void* d_ws, size_t ws_size,
                              hipStream_t stream)
{
  const float* x    = (const float*)d_in[0];
  const float* wqkv = (const float*)d_in[1];
  const float* bqkv = (const float*)d_in[2];
  const float* wo   = (const float*)d_in[3];
  const float* bo   = (const float*)d_in[4];
  float* out = (float*)d_out;
  char* ws = (char*)d_ws;

  // ws layout (bytes)
  f16*   xb    = (f16*)(ws + 0);            // 64MB (reused as A2 after GEMM1)
  f16*   wqkvT = (f16*)(ws + 67108864);     // 6MB
  float* bqkvR = (float*)(ws + 73400320);   // 12KB
  f16*   woT   = (f16*)(ws + 73412608);     // 2MB
  f16*   Qb    = (f16*)(ws + 75509760);     // 64MB
  f16*   Kb    = (f16*)(ws + 142618624);    // 64MB
  f16*   VTb   = (f16*)(ws + 209727488);    // 64MB -> total 276836352
  f16*   A2    = (f16*)(ws + 0);            // alias of xb (x dead after GEMM1)

  cvt_weights<<<16396, 256, 0, stream>>>(wqkv, bqkv, wo, wqkvT, bqkvR, woT);
  cvt_x<<<16384, 256, 0, stream>>>(x, xb);
  gemm_bt<0><<<6144, 256, 0, stream>>>(xb, wqkvT, bqkvR, Qb, Kb, VTb, nullptr, 24);
  attn64<<<8192, 64, 0, stream>>>(Qb, Kb, VTb, A2);
  gemm_bt<1><<<2048, 256, 0, stream>>>(A2, woT, bo, nullptr, nullptr, nullptr, out, 8);
}

// Round 5
// 665.554 us; speedup vs baseline: 1.1542x; 1.1542x over previous
//
#include <hip/hip_runtime.h>
#include <hip/hip_bf16.h>
#include <stdint.h>

// ---------------- problem constants ----------------
#define D_MODEL   1024
#define SEQ       8192
#define BATCH     4
#define NQKV      3072
#define HEADS     16

typedef _Float16 f16;
typedef f16   f16x8 __attribute__((ext_vector_type(8)));
typedef f16   f16x4 __attribute__((ext_vector_type(4)));
typedef float f32x4 __attribute__((ext_vector_type(4)));

#define AS1 __attribute__((address_space(1)))
#define AS3 __attribute__((address_space(3)))

__device__ __forceinline__ void lds_load16(const void* g, void* l) {
  __builtin_amdgcn_global_load_lds((const AS1 void*)g, (AS3 void*)l, 16, 0, 0);
}

// ---------------------------------------------------------------------------
// Kernel 1: convert + reorder weights (fp32 -> fp16).
// ---------------------------------------------------------------------------
__global__ void cvt_weights(const float* __restrict__ wqkv,
                            const float* __restrict__ bqkv,
                            const float* __restrict__ wo,
                            f16* __restrict__ wqkvT,
                            float* __restrict__ bqkvR,
                            f16* __restrict__ woT)
{
  const int NW1 = NQKV * D_MODEL;      // 3145728
  const int NW2 = D_MODEL * D_MODEL;   // 1048576
  int i = blockIdx.x * 256 + threadIdx.x;
  if (i < NW1) {
    int c = i % NQKV, k = i / NQKV;            // coalesced read of wqkv
    int hh = c / 192, rr = c % 192;
    int t  = rr >> 6, a = rr & 63;
    int n  = t * 1024 + hh * 64 + a;
    wqkvT[(size_t)n * 1024 + k] = (f16)wqkv[i];
  } else if (i < NW1 + NW2) {
    int j = i - NW1;
    int n = j % D_MODEL, k = j / D_MODEL;      // coalesced read of wo
    woT[(size_t)n * 1024 + k] = (f16)wo[j];
  } else if (i < NW1 + NW2 + NQKV) {
    int c = i - NW1 - NW2;
    int hh = c / 192, rr = c % 192;
    int t  = rr >> 6, a = rr & 63;
    bqkvR[t * 1024 + hh * 64 + a] = bqkv[c];
  }
}

// ---------------------------------------------------------------------------
// Kernel 2: x fp32 -> fp16 with roll(-64).
// ---------------------------------------------------------------------------
__global__ void cvt_x(const float* __restrict__ x, f16* __restrict__ xb)
{
  int i  = blockIdx.x * 256 + threadIdx.x;  // one f16x8 per thread
  int r  = i >> 7;
  int c8 = i & 127;
  int bb = r >> 13, p = r & 8191;
  int sr = (bb << 13) | ((p + 64) & 8191);
  const float* src = x + (size_t)sr * 1024 + c8 * 8;
  float4 v0 = *(const float4*)(src);
  float4 v1 = *(const float4*)(src + 4);
  f16x8 o = { (f16)v0.x, (f16)v0.y, (f16)v0.z, (f16)v0.w,
              (f16)v1.x, (f16)v1.y, (f16)v1.z, (f16)v1.w };
  *(f16x8*)(xb + (size_t)r * 1024 + c8 * 8) = o;
}

// ---------------------------------------------------------------------------
// 256x256 8-phase NT GEMM (T2+T3+T4+T5): C[M,N] = A[M,K] * B^T[N,K], K=1024.
// 512 threads = 8 waves (2m x 4n), per-wave 128x64 output. BK=64, 16 K-steps.
// LDS 128KB: 2 dbuf x { Ahalf0, Ahalf1, Bhalf0, Bhalf1 } x 16KB.
//   A-half q: tile rows with (row>>6)&1==q ; B-half q: cols with (col>>5)&1==q
// Per K-step, 4 phases (qm,qn)=(0,0),(0,1),(1,0),(1,1); each phase stages one
// half-tile >=2 barriers after that region's last reader (WAR ledger audited);
// counted vmcnt(4) once per step guarantees tile t+1 landed entering step t+1
// while keeping tile t+2's A0/B0 in flight (T4: never drain mid-loop).
// ---------------------------------------------------------------------------
#define BARX() { asm volatile("" ::: "memory"); __builtin_amdgcn_s_barrier(); \
                 __builtin_amdgcn_sched_barrier(0); }

#define LOADA(d,qm) { _Pragma("unroll") for (int mi=0;mi<4;++mi){ \
    int rr = wm*64 + mi*16 + c16; \
    const char* p = lds + (d)*65536 + (qm)*16384 + rr*128; \
    _Pragma("unroll") for (int ks=0;ks<2;++ks) \
      a[mi][ks] = *(const f16x8*)(p + ((((ks<<2)|g4) ^ (rr&7))<<4)); } }

#define LOADB(d,qn) { _Pragma("unroll") for (int nj=0;nj<2;++nj){ \
    int rr = wn*32 + nj*16 + c16; \
    const char* p = lds + (d)*65536 + 32768 + (qn)*16384 + rr*128; \
    _Pragma("unroll") for (int ks=0;ks<2;++ks) \
      b[nj][ks] = *(const f16x8*)(p + ((((ks<<2)|g4) ^ (rr&7))<<4)); } }

#define MF16(qm,qn) { __builtin_amdgcn_s_setprio(1); \
    _Pragma("unroll") for (int mi=0;mi<4;++mi) \
    _Pragma("unroll") for (int nj=0;nj<2;++nj){ \
      acc[(qm)*4+mi][(qn)*2+nj] = __builtin_amdgcn_mfma_f32_16x16x32_f16( \
          a[mi][0], b[nj][0], acc[(qm)*4+mi][(qn)*2+nj], 0,0,0); \
      acc[(qm)*4+mi][(qn)*2+nj] = __builtin_amdgcn_mfma_f32_16x16x32_f16( \
          a[mi][1], b[nj][1], acc[(qm)*4+mi][(qn)*2+nj], 0,0,0); } \
    __builtin_amdgcn_s_setprio(0); }

template<int EPI>
__global__ __launch_bounds__(512, 2)
void gemm8(const f16* __restrict__ A, const f16* __restrict__ B,
           const float* __restrict__ bias,
           f16* __restrict__ outQ, f16* __restrict__ outK,
           f16* __restrict__ outVT, float* __restrict__ outF,
           int Ntiles)
{
  __shared__ alignas(16) char lds[131072];

  int nwg  = gridDim.x;                         // divisible by 8
  int work = ((int)blockIdx.x & 7) * (nwg >> 3) + ((int)blockIdx.x >> 3);
  int mt = work / Ntiles, nt = work % Ntiles;
  int m0 = mt * 256, n0 = nt * 256;

  int tid = threadIdx.x;
  int w = tid >> 6, lane = tid & 63;
  int wm = w >> 2, wn = w & 3;
  int c16 = lane & 15, g4 = lane >> 4;

  // staging geometry: thread stages 16B chunk tid&7 of LDS row tid>>3 (and
  // row 64+(tid>>3) via second issue); source chunk pre-XOR'd so LDS chunk j
  // of row r holds global chunk j^(r&7)  (involution, rule #21).
  int rr0 = tid >> 3;
  int sc  = (((tid & 7) ^ ((tid >> 3) & 7)) << 4);
  const char* pA = (const char*)A + (size_t)(m0 + rr0) * 2048 + sc;
  const char* pB = (const char*)B + (size_t)(n0 + ((rr0 >> 5) << 6) + (rr0 & 31)) * 2048 + sc;
  char* dstA = lds + w * 1024;            // + d*65536 + qm*16384 (+8192)
  char* dstB = lds + 32768 + w * 1024;    // + d*65536 + qn*16384 (+8192)

  auto stageA = [&](int d, int qm, int t) {
    const char* s = pA + (size_t)(qm * 64) * 2048 + (size_t)t * 128;
    lds_load16(s,              dstA + d * 65536 + qm * 16384);
    lds_load16(s + 128 * 2048, dstA + d * 65536 + qm * 16384 + 8192);
  };
  auto stageB = [&](int d, int qn, int t) {
    const char* s = pB + (size_t)(qn * 32) * 2048 + (size_t)t * 128;
    lds_load16(s,              dstB + d * 65536 + qn * 16384);
    lds_load16(s + 128 * 2048, dstB + d * 65536 + qn * 16384 + 8192);
  };

  f32x4 acc[8][4];
#pragma unroll
  for (int i = 0; i < 8; ++i)
#pragma unroll
    for (int j = 0; j < 4; ++j)
      acc[i][j] = (f32x4){0.f, 0.f, 0.f, 0.f};
  f16x8 a[4][2], b[2][2];

  // prologue: tile0 fully, tile1 A0/B0; leave the last 2 stages in flight
  stageA(0, 0, 0); stageB(0, 0, 0); stageA(0, 1, 0); stageB(0, 1, 0);
  stageA(1, 0, 1); stageB(1, 0, 1);
  asm volatile("s_waitcnt vmcnt(4)" ::: "memory");
  BARX();

  for (int t = 0; t < 16; ++t) {
    int d = t & 1, e = d ^ 1;
    // phase 1: (qm0,qn0); stage A1(tile t+1 -> buf e; last read t-1:ph3)
    LOADA(d, 0); LOADB(d, 0);
    if (t < 15) stageA(e, 1, t + 1);
    BARX(); MF16(0, 0); BARX();
    // phase 2: (qm0,qn1); stage B1(tile t+1 -> buf e; last read t-1:ph4)
    LOADB(d, 1);
    if (t < 15) stageB(e, 1, t + 1);
    BARX(); MF16(0, 1); BARX();
    // phase 3: (qm1,qn0); stage A0(tile t+2 -> buf d; A0(d) last read ph1)
    LOADA(d, 1); LOADB(d, 0);
    if (t < 14) stageA(d, 0, t + 2);
    BARX(); MF16(1, 0); BARX();
    // phase 4: (qm1,qn1); stage B0(tile t+2 -> buf d; B0(d) last read ph3)
    LOADB(d, 1);
    if (t < 14) {
      stageB(d, 0, t + 2);
      asm volatile("s_waitcnt vmcnt(4)" ::: "memory");  // tile t+1 landed
    } else if (t == 14) {
      asm volatile("s_waitcnt vmcnt(0)" ::: "memory");  // drain for last step
    }
    BARX(); MF16(1, 1); BARX();
  }

  // ---------------- epilogue ----------------
  // row m = m0 + wm*128 + ai*16 + g4*4 + j ; col n = n0 + wn*64 + bj*16 + c16
  if (EPI == 0) {
    int tt = n0 >> 10;   // block-uniform: 0=Q, 1=K, 2=V
#pragma unroll
    for (int ai = 0; ai < 8; ++ai) {
#pragma unroll
      for (int bj = 0; bj < 4; ++bj) {
        int n  = n0 + wn * 64 + bj * 16 + c16;
        int nn = n & 1023;
        float bv = bias[n];
#pragma unroll
        for (int j = 0; j < 4; ++j) {
          int m = m0 + wm * 128 + ai * 16 + g4 * 4 + j;
          float v = acc[ai][bj][j] + bv;
          if (tt == 0) {
            outQ[(size_t)m * 1024 + nn] = (f16)v;
          } else if (tt == 1) {
            outK[(size_t)m * 1024 + nn] = (f16)v;
          } else {
            int sub = m >> 6, key = m & 63;
            int hh = nn >> 6, dk = nn & 63;
            outVT[(((size_t)(sub * 16 + hh) * 64 + dk) << 6) + key] = (f16)v;
          }
        }
      }
    }
  } else {
#pragma unroll
    for (int ai = 0; ai < 8; ++ai) {
#pragma unroll
      for (int bj = 0; bj < 4; ++bj) {
        int n = n0 + wn * 64 + bj * 16 + c16;
        float bv = bias[n];
#pragma unroll
        for (int j = 0; j < 4; ++j) {
          int m = m0 + wm * 128 + ai * 16 + g4 * 4 + j;
          int bb = m >> 13, p = m & 8191;
          int dr = (bb << 13) | ((p + 64) & 8191);   // roll(+64)
          outF[(size_t)dr * 1024 + n] = acc[ai][bj][j] + bv;
        }
      }
    }
  }
}

// ---------------------------------------------------------------------------
// Kernel 4: block-diagonal attention (unchanged, verified round 3).
// ---------------------------------------------------------------------------
__global__ __launch_bounds__(64)
void attn64(const f16* __restrict__ Q, const f16* __restrict__ Kb,
            const f16* __restrict__ VT, f16* __restrict__ O)
{
  __shared__ alignas(16) char plds[8192];   // P: [64][64] f16, swizzled
  int u = blockIdx.x;
  int sub = u >> 4, hh = u & 15;
  int l = threadIdx.x;
  int c = l & 15, g = l >> 4;

  const char* Qb = (const char*)Q  + (size_t)sub * 64 * 2048 + hh * 128;
  const char* KB = (const char*)Kb + (size_t)sub * 64 * 2048 + hh * 128;
  const char* VB = (const char*)VT + (size_t)u * 8192;

  f16x8 aq[4][2], bk[4][2];
#pragma unroll
  for (int mi = 0; mi < 4; ++mi)
#pragma unroll
    for (int kb = 0; kb < 2; ++kb)
      aq[mi][kb] = *(const f16x8*)(Qb + (mi * 16 + c) * 2048 + (kb * 32 + g * 8) * 2);
#pragma unroll
  for (int nj = 0; nj < 4; ++nj)
#pragma unroll
    for (int kb = 0; kb < 2; ++kb)
      bk[nj][kb] = *(const f16x8*)(KB + (nj * 16 + c) * 2048 + (kb * 32 + g * 8) * 2);

  f32x4 s[4][4];
#pragma unroll
  for (int mi = 0; mi < 4; ++mi)
#pragma unroll
    for (int nj = 0; nj < 4; ++nj)
      s[mi][nj] = (f32x4){0.f, 0.f, 0.f, 0.f};
#pragma unroll
  for (int kb = 0; kb < 2; ++kb)
#pragma unroll
    for (int mi = 0; mi < 4; ++mi)
#pragma unroll
      for (int nj = 0; nj < 4; ++nj)
        s[mi][nj] = __builtin_amdgcn_mfma_f32_16x16x32_f16(
            aq[mi][kb], bk[nj][kb], s[mi][nj], 0, 0, 0);

  const float SM_SCALE = 0.125f * 1.44269504089f;   // (1/sqrt(64))*log2(e)
#pragma unroll
  for (int mi = 0; mi < 4; ++mi) {
#pragma unroll
    for (int j = 0; j < 4; ++j) {
      float v0 = s[mi][0][j], v1 = s[mi][1][j], v2 = s[mi][2][j], v3 = s[mi][3][j];
      float mx = fmaxf(fmaxf(v0, v1), fmaxf(v2, v3));
      mx = fmaxf(mx, __shfl_xor(mx, 1));
      mx = fmaxf(mx, __shfl_xor(mx, 2));
      mx = fmaxf(mx, __shfl_xor(mx, 4));
      mx = fmaxf(mx, __shfl_xor(mx, 8));
      float p0 = exp2f((v0 - mx) * SM_SCALE);
      float p1 = exp2f((v1 - mx) * SM_SCALE);
      float p2 = exp2f((v2 - mx) * SM_SCALE);
      float p3 = exp2f((v3 - mx) * SM_SCALE);
      float sm = (p0 + p1) + (p2 + p3);
      sm += __shfl_xor(sm, 1);
      sm += __shfl_xor(sm, 2);
      sm += __shfl_xor(sm, 4);
      sm += __shfl_xor(sm, 8);
      float inv = 1.0f / sm;
      int r = mi * 16 + g * 4 + j;
      int rbyte = r * 128, rx = (r & 7) << 4;
      {
        int key = c;
        *(f16*)(plds + rbyte + (((key >> 3) << 4) ^ rx) + ((key & 7) << 1)) = (f16)(p0 * inv);
      }
      {
        int key = 16 + c;
        *(f16*)(plds + rbyte + (((key >> 3) << 4) ^ rx) + ((key & 7) << 1)) = (f16)(p1 * inv);
      }
      {
        int key = 32 + c;
        *(f16*)(plds + rbyte + (((key >> 3) << 4) ^ rx) + ((key & 7) << 1)) = (f16)(p2 * inv);
      }
      {
        int key = 48 + c;
        *(f16*)(plds + rbyte + (((key >> 3) << 4) ^ rx) + ((key & 7) << 1)) = (f16)(p3 * inv);
      }
    }
  }
  __syncthreads();

  f16x8 ap[4][2], bv[4][2];
#pragma unroll
  for (int mi = 0; mi < 4; ++mi) {
    int rowq = mi * 16 + c;
    int base = rowq * 128, rx = rowq & 7;
#pragma unroll
    for (int kb = 0; kb < 2; ++kb) {
      int ch = ((kb << 2) | g) ^ rx;
      ap[mi][kb] = *(const f16x8*)(plds + base + (ch << 4));
    }
  }
#pragma unroll
  for (int nj = 0; nj < 4; ++nj) {
    int dk = nj * 16 + c;
#pragma unroll
    for (int kb = 0; kb < 2; ++kb)
      bv[nj][kb] = *(const f16x8*)(VB + (dk * 64 + kb * 32 + g * 8) * 2);
  }

  f32x4 o[4][4];
#pragma unroll
  for (int mi = 0; mi < 4; ++mi)
#pragma unroll
    for (int nj = 0; nj < 4; ++nj)
      o[mi][nj] = (f32x4){0.f, 0.f, 0.f, 0.f};
#pragma unroll
  for (int kb = 0; kb < 2; ++kb)
#pragma unroll
    for (int mi = 0; mi < 4; ++mi)
#pragma unroll
      for (int nj = 0; nj < 4; ++nj)
        o[mi][nj] = __builtin_amdgcn_mfma_f32_16x16x32_f16(
            ap[mi][kb], bv[nj][kb], o[mi][nj], 0, 0, 0);

#pragma unroll
  for (int mi = 0; mi < 4; ++mi)
#pragma unroll
    for (int nj = 0; nj < 4; ++nj)
#pragma unroll
      for (int j = 0; j < 4; ++j) {
        int qrow = mi * 16 + g * 4 + j;
        int dk = nj * 16 + c;
        O[(size_t)(sub * 64 + qrow) * 1024 + hh * 64 + dk] = (f16)o[mi][nj][j];
      }
}

// ---------------------------------------------------------------------------
// launch
// ---------------------------------------------------------------------------
extern "C" void kernel_launch(void* const* d_in, const int* in_sizes, int n_in,
                              void* d_out, int out_size, void* d_ws, size_t ws_size,
                              hipStream_t stream)
{
  const float* x    = (const float*)d_in[0];
  const float* wqkv = (const float*)d_in[1];
  const float* bqkv = (const float*)d_in[2];
  const float* wo   = (const float*)d_in[3];
  const float* bo   = (const float*)d_in[4];
  float* out = (float*)d_out;
  char* ws = (char*)d_ws;

  // ws layout (bytes)
  f16*   xb    = (f16*)(ws + 0);            // 64MB (reused as A2 after GEMM1)
  f16*   wqkvT = (f16*)(ws + 67108864);     // 6MB
  float* bqkvR = (float*)(ws + 73400320);   // 12KB
  f16*   woT   = (f16*)(ws + 73412608);     // 2MB
  f16*   Qb    = (f16*)(ws + 75509760);     // 64MB
  f16*   Kb    = (f16*)(ws + 142618624);    // 64MB
  f16*   VTb   = (f16*)(ws + 209727488);    // 64MB -> total 276836352
  f16*   A2    = (f16*)(ws + 0);            // alias of xb (x dead after GEMM1)

  cvt_weights<<<16396, 256, 0, stream>>>(wqkv, bqkv, wo, wqkvT, bqkvR, woT);
  cvt_x<<<16384, 256, 0, stream>>>(x, xb);
  gemm8<0><<<1536, 512, 0, stream>>>(xb, wqkvT, bqkvR, Qb, Kb, VTb, nullptr, 12);
  attn64<<<8192, 64, 0, stream>>>(Qb, Kb, VTb, A2);
  gemm8<1><<<512, 512, 0, stream>>>(A2, woT, bo, nullptr, nullptr, nullptr, out, 4);
}